// Round 12
// baseline (730.568 us; speedup 1.0000x reference)
//
#include <hip/hip_runtime.h>
#include <math.h>

#define BB 32
#define NN 1024
#define MM 1024
#define FF 64
#define INF_ 1e30f
#define RING 14

typedef float f32x4 __attribute__((ext_vector_type(4)));

// ---------------- norms: one wave per row (x and y concatenated) --------------
__global__ __launch_bounds__(256) void norms_kernel(const float* __restrict__ x,
                                                    const float* __restrict__ y,
                                                    float* __restrict__ xn,
                                                    float* __restrict__ yn) {
    int gw = (blockIdx.x * 256 + threadIdx.x) >> 6;   // global wave = row index
    int lane = threadIdx.x & 63;
    int total = BB * NN + BB * MM;
    if (gw >= total) return;
    const float* src; float* dst; int row;
    if (gw < BB * NN) { src = x; dst = xn; row = gw; }
    else             { src = y; dst = yn; row = gw - BB * NN; }
    float v = src[(size_t)row * FF + lane];
    float s = v * v;
    #pragma unroll
    for (int d = 32; d > 0; d >>= 1) s += __shfl_xor(s, d, 64);
    if (lane == 0) dst[row] = s;
}

// ------- cost: 64x64 tile per 256-thread block; PERMUTED SHEARED store --------
// sheared row sg = (row+col)&1023 holds cell i=row at PERMUTED position
//   pos(i) = ((i>>2)&3)*256 + (i>>4)*4 + (i&3)
// so the DP kernel's global_load_lds chunks (4 x 1KB contiguous) land such that
// lane l's 16 cells are 4 conflict-free ds_read_b128 at dword k*256 + l*4.
__global__ __launch_bounds__(256) void cost_kernel(const float* __restrict__ x,
                                                   const float* __restrict__ y,
                                                   const float* __restrict__ xn,
                                                   const float* __restrict__ yn,
                                                   float* __restrict__ cost) {
    __shared__ float Xs[FF][68];   // [k][row], padded
    __shared__ float Ys[FF][68];
    const int b    = blockIdx.z;
    const int row0 = blockIdx.y * 64;
    const int col0 = blockIdx.x * 64;
    const int tid  = threadIdx.x;
    const float* xb = x + (size_t)b * NN * FF;
    const float* yb = y + (size_t)b * MM * FF;

    #pragma unroll
    for (int cc = 0; cc < 4; ++cc) {
        int s  = tid + cc * 256;      // 0..1023 float4 slots
        int r  = s >> 4;              // tile row 0..63
        int kq = s & 15;              // k-quad 0..15
        float4 vx = *(const float4*)(xb + (size_t)(row0 + r) * FF + kq * 4);
        float4 vy = *(const float4*)(yb + (size_t)(col0 + r) * FF + kq * 4);
        Xs[kq*4+0][r] = vx.x; Xs[kq*4+1][r] = vx.y; Xs[kq*4+2][r] = vx.z; Xs[kq*4+3][r] = vx.w;
        Ys[kq*4+0][r] = vy.x; Ys[kq*4+1][r] = vy.y; Ys[kq*4+2][r] = vy.z; Ys[kq*4+3][r] = vy.w;
    }
    __syncthreads();

    const int tx = tid & 15, ty = tid >> 4;
    float acc[4][4] = {};
    #pragma unroll 16
    for (int k = 0; k < FF; ++k) {
        float4 a  = *(const float4*)&Xs[k][ty * 4];
        float4 bb = *(const float4*)&Ys[k][tx * 4];
        float av[4] = {a.x, a.y, a.z, a.w};
        float bv[4] = {bb.x, bb.y, bb.z, bb.w};
        #pragma unroll
        for (int r = 0; r < 4; ++r)
            #pragma unroll
            for (int c = 0; c < 4; ++c)
                acc[r][c] += av[r] * bv[c];
    }

    float* cD = cost + (size_t)b * NN * MM;
    #pragma unroll
    for (int r = 0; r < 4; ++r) {
        int row = row0 + ty * 4 + r;
        float xnv = xn[b * NN + row];
        int pos = ((row >> 2) & 3) * 256 + (row >> 4) * 4 + (row & 3);
        #pragma unroll
        for (int c = 0; c < 4; ++c) {
            int col = col0 + tx * 4 + c;
            float v = xnv + yn[b * MM + col] - 2.0f * acc[r][c];
            v = sqrtf(fmaxf(v, 0.0f));
            cD[(size_t)((row + col) & 1023) * MM + pos] = v;   // permuted shear
        }
    }
}

// ---------------- DPP shift (gfx9 encoding, live on gfx950) -------------------
__device__ __forceinline__ float dpp_wave_shr1(float v, float oldv) {
    // lane i <- lane i-1; lane 0 <- oldv  (bound_ctrl=false keeps old)
    int t = __builtin_amdgcn_update_dpp(__float_as_int(oldv), __float_as_int(v),
                                        0x138, 0xf, 0xf, false);
    return __int_as_float(t);
}

// ---------------- DTW DP over anti-diagonals: one wave per batch --------------
// 14-row LDS ring via global_load_lds (56 loads in flight <= 63 vmcnt cap).
// Each row = 4 x 1KB contiguous chunks (coalesced); HW dest = ldsbase+lane*16.
// ds_reads are pipelined one step ahead (C0/C1 double buffer); min3 chain runs
// before the vmcnt to hide part of the stall. Low VGPR -> regalloc never
// touches in-flight data (the R8/R10 corruption class is structurally gone).
__global__ __launch_bounds__(64)
__attribute__((amdgpu_waves_per_eu(1, 1)))
void dtw_diag_kernel(const float* __restrict__ cost, float* __restrict__ out) {
    __shared__ float ring[RING * 1024];
    const int b    = blockIdx.x;
    const int lane = threadIdx.x;
    const float* cbD = cost + (size_t)b * NN * MM;

    // stage one sheared row (4KB) into ring slot: 4 contiguous 1KB chunks
    #define GLL_ROW(NRROW, SLOT)                                               \
    {                                                                          \
        const float* rb_ = cbD + (size_t)(NRROW) * MM;                         \
        _Pragma("unroll")                                                      \
        for (int k_ = 0; k_ < 4; ++k_) {                                       \
            __builtin_amdgcn_global_load_lds(                                  \
                (const __attribute__((address_space(1))) void*)(rb_ + k_ * 256 + lane * 4), \
                (__attribute__((address_space(3))) void*)(&ring[(SLOT) * 1024 + k_ * 256]), \
                16, 0, 0);                                                     \
        }                                                                      \
    }

    // prologue: fill ring slots 0..13 with rows 0..13
    #pragma unroll
    for (int rr = 0; rr < RING; ++rr) GLL_ROW(rr, rr)

    float A[16], B[16], C0[16], C1[16];
    #pragma unroll
    for (int j = 0; j < 16; ++j) { A[j] = INF_; B[j] = INF_; }
    float bnd = 0.0f;    // diag-neighbor injected at (0,0) only; INF_ afterwards

    // prime C0 with row 0 (slot 0)
    asm volatile("s_waitcnt vmcnt(52)" ::: "memory");
    {
        #pragma unroll
        for (int k = 0; k < 4; ++k) {
            float4 n = *(const float4*)&ring[k * 256 + lane * 4];
            C0[4*k+0] = n.x; C0[4*k+1] = n.y; C0[4*k+2] = n.z; C0[4*k+3] = n.w;
        }
    }

    // one diagonal step: t-chain (A/B only) -> vmcnt -> ds_read next row ->
    // P2 = CC + t -> reissue gll into the slot just consumed.
    #define DIAG_STEP(SLOT_CUR, SLOT_NXT, PV, P2, CC, CCN, NRROW)              \
    {                                                                          \
        float pvm1 = dpp_wave_shr1(PV[15], INF_);                              \
        float p2m1 = dpp_wave_shr1(P2[15], bnd);                               \
        float t[16];                                                           \
        _Pragma("unroll")                                                      \
        for (int r = 0; r < 16; ++r) {                                         \
            float pv_r = PV[r], p2_r = P2[r];                                  \
            t[r] = fminf(fminf(pv_r, pvm1), p2m1);                             \
            pvm1 = pv_r; p2m1 = p2_r;                                          \
        }                                                                      \
        asm volatile("s_waitcnt vmcnt(48)" ::: "memory");                      \
        float4 n0 = *(const float4*)&ring[(SLOT_NXT) * 1024 + 0 * 256 + lane * 4]; \
        float4 n1 = *(const float4*)&ring[(SLOT_NXT) * 1024 + 1 * 256 + lane * 4]; \
        float4 n2 = *(const float4*)&ring[(SLOT_NXT) * 1024 + 2 * 256 + lane * 4]; \
        float4 n3 = *(const float4*)&ring[(SLOT_NXT) * 1024 + 3 * 256 + lane * 4]; \
        _Pragma("unroll")                                                      \
        for (int r = 0; r < 16; ++r) P2[r] = CC[r] + t[r];                     \
        GLL_ROW(NRROW, SLOT_CUR)                                               \
        CCN[0]  = n0.x; CCN[1]  = n0.y; CCN[2]  = n0.z; CCN[3]  = n0.w;        \
        CCN[4]  = n1.x; CCN[5]  = n1.y; CCN[6]  = n1.z; CCN[7]  = n1.w;        \
        CCN[8]  = n2.x; CCN[9]  = n2.y; CCN[10] = n2.z; CCN[11] = n2.w;        \
        CCN[12] = n3.x; CCN[13] = n3.y; CCN[14] = n3.z; CCN[15] = n3.w;        \
    }

    // 14-step block: slot j, parity alternates (A,B,C0,C1 / B,A,C1,C0)
    #define BLOCK14(D0)                                                        \
        DIAG_STEP(0,  1,  A, B, C0, C1, (((D0) + 14) & 1023))                  \
        DIAG_STEP(1,  2,  B, A, C1, C0, (((D0) + 15) & 1023))                  \
        DIAG_STEP(2,  3,  A, B, C0, C1, (((D0) + 16) & 1023))                  \
        DIAG_STEP(3,  4,  B, A, C1, C0, (((D0) + 17) & 1023))                  \
        DIAG_STEP(4,  5,  A, B, C0, C1, (((D0) + 18) & 1023))                  \
        DIAG_STEP(5,  6,  B, A, C1, C0, (((D0) + 19) & 1023))                  \
        DIAG_STEP(6,  7,  A, B, C0, C1, (((D0) + 20) & 1023))                  \
        DIAG_STEP(7,  8,  B, A, C1, C0, (((D0) + 21) & 1023))                  \
        DIAG_STEP(8,  9,  A, B, C0, C1, (((D0) + 22) & 1023))                  \
        DIAG_STEP(9,  10, B, A, C1, C0, (((D0) + 23) & 1023))                  \
        DIAG_STEP(10, 11, A, B, C0, C1, (((D0) + 24) & 1023))                  \
        DIAG_STEP(11, 12, B, A, C1, C0, (((D0) + 25) & 1023))                  \
        DIAG_STEP(12, 13, A, B, C0, C1, (((D0) + 26) & 1023))                  \
        DIAG_STEP(13, 0,  B, A, C1, C0, (((D0) + 27) & 1023))

    // peel first block (d = 0..13) so bnd flips after step 0
    DIAG_STEP(0,  1,  A, B, C0, C1, 14)   bnd = INF_;
    DIAG_STEP(1,  2,  B, A, C1, C0, 15)
    DIAG_STEP(2,  3,  A, B, C0, C1, 16)
    DIAG_STEP(3,  4,  B, A, C1, C0, 17)
    DIAG_STEP(4,  5,  A, B, C0, C1, 18)
    DIAG_STEP(5,  6,  B, A, C1, C0, 19)
    DIAG_STEP(6,  7,  A, B, C0, C1, 20)
    DIAG_STEP(7,  8,  B, A, C1, C0, 21)
    DIAG_STEP(8,  9,  A, B, C0, C1, 22)
    DIAG_STEP(9,  10, B, A, C1, C0, 23)
    DIAG_STEP(10, 11, A, B, C0, C1, 24)
    DIAG_STEP(11, 12, B, A, C1, C0, 25)
    DIAG_STEP(12, 13, A, B, C0, C1, 26)
    DIAG_STEP(13, 0,  B, A, C1, C0, 27)

    // main: d0 = 14..2030 step 14 (145 blocks -> diags 14..2043)
    for (int d0 = 14; d0 < 2044; d0 += 14) {
        BLOCK14(d0)
    }

    // tail: diags 2044..2046 (slots 0,1,2; dummy reissues keep vmcnt invariant)
    DIAG_STEP(0, 1, A, B, C0, C1, 10)
    DIAG_STEP(1, 2, B, A, C1, C0, 11)
    DIAG_STEP(2, 3, A, B, C0, C1, 12)   // diag 2046 writes B
    #undef DIAG_STEP
    #undef BLOCK14
    #undef GLL_ROW

    if (lane == 63) out[b] = B[15];
}

// ---------------- fused fallback (no workspace): cost on the fly --------------
__global__ __launch_bounds__(1024) void dtw_fused_kernel(const float* __restrict__ x,
                                                         const float* __restrict__ y,
                                                         float* __restrict__ out) {
    const int b    = blockIdx.x;
    const int tid  = threadIdx.x;
    const int lane = tid & 63;
    const int wid  = tid >> 6;
    __shared__ float P[MM];
    __shared__ float xrow[FF];
    __shared__ float part_sum[16];
    __shared__ float part_min[16];

    float yr[FF];
    const float* yrow = y + ((size_t)b * MM + tid) * FF;
    #pragma unroll
    for (int q = 0; q < FF / 4; ++q) {
        float4 v = ((const float4*)yrow)[q];
        yr[q*4+0] = v.x; yr[q*4+1] = v.y; yr[q*4+2] = v.z; yr[q*4+3] = v.w;
    }

    P[tid] = INF_;
    __syncthreads();

    const float* xb = x + (size_t)b * NN * FF;
    float result = 0.0f;

    for (int i = 0; i < NN; ++i) {
        if (tid < FF) xrow[tid] = xb[(size_t)i * FF + tid];
        float up   = P[tid];
        float diag = (tid == 0) ? (i == 0 ? 0.0f : INF_) : P[tid - 1];
        float m    = fminf(up, diag);
        __syncthreads();

        float ss = 0.0f;
        #pragma unroll 16
        for (int k = 0; k < FF; ++k) {
            float d = xrow[k] - yr[k];
            ss += d * d;
        }
        float c = sqrtf(ss);

        float s = c;
        #pragma unroll
        for (int d = 1; d < 64; d <<= 1) {
            float t = __shfl_up(s, d, 64);
            if (lane >= d) s += t;
        }
        if (lane == 63) part_sum[wid] = s;
        __syncthreads();
        if (tid < 16) {
            float p = part_sum[tid];
            #pragma unroll
            for (int d = 1; d < 16; d <<= 1) {
                float t = __shfl_up(p, d, 64);
                if (tid >= d) p += t;
            }
            part_sum[tid] = p;
        }
        __syncthreads();
        float C = s + (wid > 0 ? part_sum[wid - 1] : 0.0f);

        float z = c + m - C;
        float w = z;
        #pragma unroll
        for (int d = 1; d < 64; d <<= 1) {
            float t = __shfl_up(w, d, 64);
            if (lane >= d) w = fminf(w, t);
        }
        if (lane == 63) part_min[wid] = w;
        __syncthreads();
        if (tid < 16) {
            float p = part_min[tid];
            #pragma unroll
            for (int d = 1; d < 16; d <<= 1) {
                float t = __shfl_up(p, d, 64);
                if (tid >= d) p = fminf(p, t);
            }
            part_min[tid] = p;
        }
        __syncthreads();
        float wm  = (wid > 0) ? fminf(w, part_min[wid - 1]) : w;
        float cur = C + wm;

        P[tid] = cur;
        __syncthreads();
        if (i == NN - 1 && tid == MM - 1) result = cur;
    }
    if (tid == MM - 1) out[b] = result;
}

extern "C" void kernel_launch(void* const* d_in, const int* in_sizes, int n_in,
                              void* d_out, int out_size, void* d_ws, size_t ws_size,
                              hipStream_t stream) {
    const float* x = (const float*)d_in[0];
    const float* y = (const float*)d_in[1];
    float* out = (float*)d_out;

    size_t need = (size_t)BB * NN * MM * sizeof(float)
                + (size_t)BB * NN * sizeof(float)
                + (size_t)BB * MM * sizeof(float);

    if (ws_size >= need) {
        float* cost = (float*)d_ws;
        float* xn = cost + (size_t)BB * NN * MM;
        float* yn = xn + (size_t)BB * NN;

        int total_rows = BB * NN + BB * MM;
        int blocks = (total_rows + 3) / 4;
        hipLaunchKernelGGL(norms_kernel, dim3(blocks), dim3(256), 0, stream,
                           x, y, xn, yn);
        hipLaunchKernelGGL(cost_kernel, dim3(MM / 64, NN / 64, BB), dim3(256), 0, stream,
                           x, y, xn, yn, cost);
        hipLaunchKernelGGL(dtw_diag_kernel, dim3(BB), dim3(64), 0, stream, cost, out);
    } else {
        hipLaunchKernelGGL(dtw_fused_kernel, dim3(BB), dim3(1024), 0, stream, x, y, out);
    }
}

// Round 13
// 302.776 us; speedup vs baseline: 2.4129x; 2.4129x over previous
//
#include <hip/hip_runtime.h>
#include <hip/hip_fp16.h>
#include <math.h>

#define BB 32
#define NN 1024
#define MM 1024
#define FF 64
#define INF_ 1e30f

typedef float f32x4 __attribute__((ext_vector_type(4)));

// ---------------- norms: one wave per row (x and y concatenated) --------------
__global__ __launch_bounds__(256) void norms_kernel(const float* __restrict__ x,
                                                    const float* __restrict__ y,
                                                    float* __restrict__ xn,
                                                    float* __restrict__ yn) {
    int gw = (blockIdx.x * 256 + threadIdx.x) >> 6;   // global wave = row index
    int lane = threadIdx.x & 63;
    int total = BB * NN + BB * MM;
    if (gw >= total) return;
    const float* src; float* dst; int row;
    if (gw < BB * NN) { src = x; dst = xn; row = gw; }
    else             { src = y; dst = yn; row = gw - BB * NN; }
    float v = src[(size_t)row * FF + lane];
    float s = v * v;
    #pragma unroll
    for (int d = 32; d > 0; d >>= 1) s += __shfl_xor(s, d, 64);
    if (lane == 0) dst[row] = s;
}

// ------- cost: 64x64 tile per 256-thread block; SHEARED fp16 store ------------
// costD[((row+col)&1023)*MM + row] = (half)cost[row][col]
__global__ __launch_bounds__(256) void cost_kernel(const float* __restrict__ x,
                                                   const float* __restrict__ y,
                                                   const float* __restrict__ xn,
                                                   const float* __restrict__ yn,
                                                   __half* __restrict__ cost) {
    __shared__ float Xs[FF][68];   // [k][row], padded
    __shared__ float Ys[FF][68];
    const int b    = blockIdx.z;
    const int row0 = blockIdx.y * 64;
    const int col0 = blockIdx.x * 64;
    const int tid  = threadIdx.x;
    const float* xb = x + (size_t)b * NN * FF;
    const float* yb = y + (size_t)b * MM * FF;

    #pragma unroll
    for (int cc = 0; cc < 4; ++cc) {
        int s  = tid + cc * 256;      // 0..1023 float4 slots
        int r  = s >> 4;              // tile row 0..63
        int kq = s & 15;              // k-quad 0..15
        float4 vx = *(const float4*)(xb + (size_t)(row0 + r) * FF + kq * 4);
        float4 vy = *(const float4*)(yb + (size_t)(col0 + r) * FF + kq * 4);
        Xs[kq*4+0][r] = vx.x; Xs[kq*4+1][r] = vx.y; Xs[kq*4+2][r] = vx.z; Xs[kq*4+3][r] = vx.w;
        Ys[kq*4+0][r] = vy.x; Ys[kq*4+1][r] = vy.y; Ys[kq*4+2][r] = vy.z; Ys[kq*4+3][r] = vy.w;
    }
    __syncthreads();

    const int tx = tid & 15, ty = tid >> 4;
    float acc[4][4] = {};
    #pragma unroll 16
    for (int k = 0; k < FF; ++k) {
        float4 a  = *(const float4*)&Xs[k][ty * 4];
        float4 bb = *(const float4*)&Ys[k][tx * 4];
        float av[4] = {a.x, a.y, a.z, a.w};
        float bv[4] = {bb.x, bb.y, bb.z, bb.w};
        #pragma unroll
        for (int r = 0; r < 4; ++r)
            #pragma unroll
            for (int c = 0; c < 4; ++c)
                acc[r][c] += av[r] * bv[c];
    }

    __half* cD = cost + (size_t)b * NN * MM;
    #pragma unroll
    for (int r = 0; r < 4; ++r) {
        int row = row0 + ty * 4 + r;
        float xnv = xn[b * NN + row];
        #pragma unroll
        for (int c = 0; c < 4; ++c) {
            int col = col0 + tx * 4 + c;
            float v = xnv + yn[b * MM + col] - 2.0f * acc[r][c];
            v = sqrtf(fmaxf(v, 0.0f));
            cD[(size_t)((row + col) & 1023) * MM + row] = __float2half(v);
        }
    }
}

// ---------------- DPP shift (gfx9 encoding, live on gfx950) -------------------
__device__ __forceinline__ float dpp_wave_shr1(float v, float oldv) {
    // lane i <- lane i-1; lane 0 <- oldv  (bound_ctrl=false keeps old)
    int t = __builtin_amdgcn_update_dpp(__float_as_int(oldv), __float_as_int(v),
                                        0x138, 0xf, 0xf, false);
    return __int_as_float(t);
}

// ---------------- fp16 row buffer, asm-issued loads ---------------------------
struct RowBufH { f32x4 q0, q1; };   // raw 8 dwords = 16 halfs

__device__ __forceinline__ void issue_rowh(RowBufH& R, const __half* rowbase,
                                           unsigned voff) {
    asm volatile(
        "global_load_dwordx4 %0, %2, %3\n\t"
        "global_load_dwordx4 %1, %2, %3 offset:16"
        : "=v"(R.q0), "=v"(R.q1)
        : "v"(voff), "s"(rowbase));
}

__device__ __forceinline__ void unpack16(const RowBufH& R, float cc[16]) {
    #pragma unroll
    for (int q = 0; q < 4; ++q) {
        unsigned w0 = __float_as_uint(R.q0[q]);
        unsigned w1 = __float_as_uint(R.q1[q]);
        __half2 h0 = *reinterpret_cast<__half2*>(&w0);
        __half2 h1 = *reinterpret_cast<__half2*>(&w1);
        cc[2*q+0]   = __low2float(h0);  cc[2*q+1]   = __high2float(h0);
        cc[8+2*q+0] = __low2float(h1);  cc[8+2*q+1] = __high2float(h1);
    }
}

// ---------------- DTW DP over anti-diagonals: one wave per batch --------------
// lane l owns rows i in [16l, 16l+16). At diagonal d, slot i computes cell
// (i, d-i):  cur[i] = c[i] + min(prev[i], prev[i-1], prev2[i-1]).
// fp16 8-row ring: 16 requests in flight, vmcnt(14)/step (oldest row landed).
// Live set ~120 VGPR — safely under the allocator's resident cap (no spill of
// async asm outputs = no R8/R10 corruption class). Compute-before-wait: the
// min3 chain depends only on A/B and runs before the vmcnt.
__global__ __launch_bounds__(64)
__attribute__((amdgpu_waves_per_eu(1, 1)))
void dtw_diag_kernel(const __half* __restrict__ cost, float* __restrict__ out) {
    const int b    = blockIdx.x;
    const int lane = threadIdx.x;
    const __half* cbD = cost + (size_t)b * NN * MM;   // uniform across wave
    const unsigned voff = (unsigned)lane * 32u;       // 16 halfs/lane

    RowBufH R0, R1, R2, R3, R4, R5, R6, R7;
    issue_rowh(R0, cbD + 0 * (size_t)MM, voff);
    issue_rowh(R1, cbD + 1 * (size_t)MM, voff);
    issue_rowh(R2, cbD + 2 * (size_t)MM, voff);
    issue_rowh(R3, cbD + 3 * (size_t)MM, voff);
    issue_rowh(R4, cbD + 4 * (size_t)MM, voff);
    issue_rowh(R5, cbD + 5 * (size_t)MM, voff);
    issue_rowh(R6, cbD + 6 * (size_t)MM, voff);
    issue_rowh(R7, cbD + 7 * (size_t)MM, voff);

    float A[16], B[16];
    #pragma unroll
    for (int j = 0; j < 16; ++j) { A[j] = INF_; B[j] = INF_; }
    float bnd = 0.0f;    // diag-neighbor injected at (0,0) only; INF_ afterwards

    // one diagonal: min3 chain first (A/B only), THEN wait oldest buffer,
    // unpack + add, then reissue (NR always a valid row)
    #define DIAG_STEP(Rk, PV, P2, NR)                                          \
    {                                                                          \
        float pvm1 = dpp_wave_shr1(PV[15], INF_);                              \
        float p2m1 = dpp_wave_shr1(P2[15], bnd);                               \
        float t[16];                                                           \
        _Pragma("unroll")                                                      \
        for (int r = 0; r < 16; ++r) {                                         \
            float pv_r = PV[r], p2_r = P2[r];                                  \
            t[r] = fminf(fminf(pv_r, pvm1), p2m1);                             \
            pvm1 = pv_r; p2m1 = p2_r;                                          \
        }                                                                      \
        asm volatile("s_waitcnt vmcnt(14)" ::: "memory");                      \
        __builtin_amdgcn_sched_barrier(0);                                     \
        float cc[16]; unpack16(Rk, cc);                                        \
        _Pragma("unroll")                                                      \
        for (int r = 0; r < 16; ++r) P2[r] = cc[r] + t[r];                     \
        __builtin_amdgcn_sched_barrier(0);                                     \
        issue_rowh(Rk, cbD + (size_t)(NR) * MM, voff);                         \
    }

    // peel first 8 diagonals (d = 0..7); bnd -> INF_ after d = 0
    DIAG_STEP(R0, A, B, 8)   bnd = INF_;
    DIAG_STEP(R1, B, A, 9)
    DIAG_STEP(R2, A, B, 10)
    DIAG_STEP(R3, B, A, 11)
    DIAG_STEP(R4, A, B, 12)
    DIAG_STEP(R5, B, A, 13)
    DIAG_STEP(R6, A, B, 14)
    DIAG_STEP(R7, B, A, 15)

    for (int d0 = 8; d0 < 2040; d0 += 8) {
        DIAG_STEP(R0, A, B, ((d0 +  8) & 1023))
        DIAG_STEP(R1, B, A, ((d0 +  9) & 1023))
        DIAG_STEP(R2, A, B, ((d0 + 10) & 1023))
        DIAG_STEP(R3, B, A, ((d0 + 11) & 1023))
        DIAG_STEP(R4, A, B, ((d0 + 12) & 1023))
        DIAG_STEP(R5, B, A, ((d0 + 13) & 1023))
        DIAG_STEP(R6, A, B, ((d0 + 14) & 1023))
        DIAG_STEP(R7, B, A, ((d0 + 15) & 1023))
    }

    // tail: d = 2040..2046 (reissued rows are dummies, keeps vmcnt invariant)
    DIAG_STEP(R0, A, B, 0)
    DIAG_STEP(R1, B, A, 1)
    DIAG_STEP(R2, A, B, 2)
    DIAG_STEP(R3, B, A, 3)
    DIAG_STEP(R4, A, B, 4)
    DIAG_STEP(R5, B, A, 5)
    DIAG_STEP(R6, A, B, 6)          // d = 2046 writes B; D(1023,1023) = B[15]@lane63
    #undef DIAG_STEP

    if (lane == 63) out[b] = B[15];
}

// ---------------- fused fallback (no workspace): cost on the fly --------------
__global__ __launch_bounds__(1024) void dtw_fused_kernel(const float* __restrict__ x,
                                                         const float* __restrict__ y,
                                                         float* __restrict__ out) {
    const int b    = blockIdx.x;
    const int tid  = threadIdx.x;
    const int lane = tid & 63;
    const int wid  = tid >> 6;
    __shared__ float P[MM];
    __shared__ float xrow[FF];
    __shared__ float part_sum[16];
    __shared__ float part_min[16];

    float yr[FF];
    const float* yrow = y + ((size_t)b * MM + tid) * FF;
    #pragma unroll
    for (int q = 0; q < FF / 4; ++q) {
        float4 v = ((const float4*)yrow)[q];
        yr[q*4+0] = v.x; yr[q*4+1] = v.y; yr[q*4+2] = v.z; yr[q*4+3] = v.w;
    }

    P[tid] = INF_;
    __syncthreads();

    const float* xb = x + (size_t)b * NN * FF;
    float result = 0.0f;

    for (int i = 0; i < NN; ++i) {
        if (tid < FF) xrow[tid] = xb[(size_t)i * FF + tid];
        float up   = P[tid];
        float diag = (tid == 0) ? (i == 0 ? 0.0f : INF_) : P[tid - 1];
        float m    = fminf(up, diag);
        __syncthreads();

        float ss = 0.0f;
        #pragma unroll 16
        for (int k = 0; k < FF; ++k) {
            float d = xrow[k] - yr[k];
            ss += d * d;
        }
        float c = sqrtf(ss);

        float s = c;
        #pragma unroll
        for (int d = 1; d < 64; d <<= 1) {
            float t = __shfl_up(s, d, 64);
            if (lane >= d) s += t;
        }
        if (lane == 63) part_sum[wid] = s;
        __syncthreads();
        if (tid < 16) {
            float p = part_sum[tid];
            #pragma unroll
            for (int d = 1; d < 16; d <<= 1) {
                float t = __shfl_up(p, d, 64);
                if (tid >= d) p += t;
            }
            part_sum[tid] = p;
        }
        __syncthreads();
        float C = s + (wid > 0 ? part_sum[wid - 1] : 0.0f);

        float z = c + m - C;
        float w = z;
        #pragma unroll
        for (int d = 1; d < 64; d <<= 1) {
            float t = __shfl_up(w, d, 64);
            if (lane >= d) w = fminf(w, t);
        }
        if (lane == 63) part_min[wid] = w;
        __syncthreads();
        if (tid < 16) {
            float p = part_min[tid];
            #pragma unroll
            for (int d = 1; d < 16; d <<= 1) {
                float t = __shfl_up(p, d, 64);
                if (tid >= d) p = fminf(p, t);
            }
            part_min[tid] = p;
        }
        __syncthreads();
        float wm  = (wid > 0) ? fminf(w, part_min[wid - 1]) : w;
        float cur = C + wm;

        P[tid] = cur;
        __syncthreads();
        if (i == NN - 1 && tid == MM - 1) result = cur;
    }
    if (tid == MM - 1) out[b] = result;
}

extern "C" void kernel_launch(void* const* d_in, const int* in_sizes, int n_in,
                              void* d_out, int out_size, void* d_ws, size_t ws_size,
                              hipStream_t stream) {
    const float* x = (const float*)d_in[0];
    const float* y = (const float*)d_in[1];
    float* out = (float*)d_out;

    size_t cost_bytes = (size_t)BB * NN * MM * sizeof(__half);
    size_t need = cost_bytes
                + (size_t)BB * NN * sizeof(float)
                + (size_t)BB * MM * sizeof(float);

    if (ws_size >= need) {
        __half* cost = (__half*)d_ws;
        float* xn = (float*)((char*)d_ws + cost_bytes);
        float* yn = xn + (size_t)BB * NN;

        int total_rows = BB * NN + BB * MM;
        int blocks = (total_rows + 3) / 4;
        hipLaunchKernelGGL(norms_kernel, dim3(blocks), dim3(256), 0, stream,
                           x, y, xn, yn);
        hipLaunchKernelGGL(cost_kernel, dim3(MM / 64, NN / 64, BB), dim3(256), 0, stream,
                           x, y, xn, yn, cost);
        hipLaunchKernelGGL(dtw_diag_kernel, dim3(BB), dim3(64), 0, stream, cost, out);
    } else {
        hipLaunchKernelGGL(dtw_fused_kernel, dim3(BB), dim3(1024), 0, stream, x, y, out);
    }
}

// Round 15
// 291.510 us; speedup vs baseline: 2.5061x; 1.0386x over previous
//
#include <hip/hip_runtime.h>
#include <math.h>

#define BB 32
#define NN 1024
#define MM 1024
#define FF 64
#define INF_ 1e30f

typedef float f32x4 __attribute__((ext_vector_type(4)));

// ------- cost: 64x64 tile per 256-thread block; SHEARED fp32 store ------------
// costD[((row+col)&1023)*MM + row] = cost[row][col]  (bijective, same 4MB/batch)
// Norms are computed in-block from the staged LDS tiles (norms kernel fused).
__global__ __launch_bounds__(256) void cost_kernel(const float* __restrict__ x,
                                                   const float* __restrict__ y,
                                                   float* __restrict__ cost) {
    __shared__ float Xs[FF][68];   // [k][row], padded
    __shared__ float Ys[FF][68];
    __shared__ float xnl[64];
    __shared__ float ynl[64];
    const int b    = blockIdx.z;
    const int row0 = blockIdx.y * 64;
    const int col0 = blockIdx.x * 64;
    const int tid  = threadIdx.x;
    const float* xb = x + (size_t)b * NN * FF;
    const float* yb = y + (size_t)b * MM * FF;

    #pragma unroll
    for (int cc = 0; cc < 4; ++cc) {
        int s  = tid + cc * 256;      // 0..1023 float4 slots
        int r  = s >> 4;              // tile row 0..63
        int kq = s & 15;              // k-quad 0..15
        float4 vx = *(const float4*)(xb + (size_t)(row0 + r) * FF + kq * 4);
        float4 vy = *(const float4*)(yb + (size_t)(col0 + r) * FF + kq * 4);
        Xs[kq*4+0][r] = vx.x; Xs[kq*4+1][r] = vx.y; Xs[kq*4+2][r] = vx.z; Xs[kq*4+3][r] = vx.w;
        Ys[kq*4+0][r] = vy.x; Ys[kq*4+1][r] = vy.y; Ys[kq*4+2][r] = vy.z; Ys[kq*4+3][r] = vy.w;
    }
    __syncthreads();

    // fused norms: wave 0 -> xnl, wave 1 -> ynl (consecutive-lane LDS reads,
    // conflict-free); other waves proceed straight to the MAC loop.
    if (tid < 64) {
        float s = 0.0f;
        #pragma unroll 16
        for (int k = 0; k < FF; ++k) { float v = Xs[k][tid]; s += v * v; }
        xnl[tid] = s;
    } else if (tid < 128) {
        int r = tid - 64;
        float s = 0.0f;
        #pragma unroll 16
        for (int k = 0; k < FF; ++k) { float v = Ys[k][r]; s += v * v; }
        ynl[r] = s;
    }

    const int tx = tid & 15, ty = tid >> 4;
    float acc[4][4] = {};
    #pragma unroll 16
    for (int k = 0; k < FF; ++k) {
        float4 a  = *(const float4*)&Xs[k][ty * 4];
        float4 bb = *(const float4*)&Ys[k][tx * 4];
        float av[4] = {a.x, a.y, a.z, a.w};
        float bv[4] = {bb.x, bb.y, bb.z, bb.w};
        #pragma unroll
        for (int r = 0; r < 4; ++r)
            #pragma unroll
            for (int c = 0; c < 4; ++c)
                acc[r][c] += av[r] * bv[c];
    }
    __syncthreads();   // norms visible to all

    float* cD = cost + (size_t)b * NN * MM;
    #pragma unroll
    for (int r = 0; r < 4; ++r) {
        int rl  = ty * 4 + r;
        int row = row0 + rl;
        float xnv = xnl[rl];
        #pragma unroll
        for (int c = 0; c < 4; ++c) {
            int cl  = tx * 4 + c;
            int col = col0 + cl;
            float v = xnv + ynl[cl] - 2.0f * acc[r][c];
            v = sqrtf(fmaxf(v, 0.0f));
            cD[(size_t)((row + col) & 1023) * MM + row] = v;   // sheared
        }
    }
}

// ---------------- DPP shift (gfx9 encoding, live on gfx950) -------------------
__device__ __forceinline__ float dpp_wave_shr1(float v, float oldv) {
    // lane i <- lane i-1; lane 0 <- oldv  (bound_ctrl=false keeps old)
    int t = __builtin_amdgcn_update_dpp(__float_as_int(oldv), __float_as_int(v),
                                        0x138, 0xf, 0xf, false);
    return __int_as_float(t);
}

// ---------------- register diag buffer, asm-issued loads ----------------------
struct RowBuf { f32x4 q0, q1, q2, q3; };

__device__ __forceinline__ void issue_row(RowBuf& R, const float* rowbase,
                                          unsigned voff) {
    asm volatile(
        "global_load_dwordx4 %0, %4, %5\n\t"
        "global_load_dwordx4 %1, %4, %5 offset:16\n\t"
        "global_load_dwordx4 %2, %4, %5 offset:32\n\t"
        "global_load_dwordx4 %3, %4, %5 offset:48"
        : "=v"(R.q0), "=v"(R.q1), "=v"(R.q2), "=v"(R.q3)
        : "v"(voff), "s"(rowbase));
}

// touch-prefetch: one dword per lane at 64B stride covers all lines of the 4KB
// row; warms L2 / MSHR-merges with the real load issued 8 steps later.
// "+v" (read-write) chains every touch through ONE virtual register whose live
// range extends to the terminal use at kernel end -> regalloc reserves one
// physical VGPR for it, so the async landing write can never clobber live data
// (the R14 failure: "=v" output was dead -> register reused -> corrupted).
__device__ __forceinline__ void touch_row(float& dummy, const float* rowbase,
                                          unsigned voff) {
    asm volatile("global_load_dword %0, %1, %2"
                 : "+v"(dummy) : "v"(voff), "s"(rowbase));
}

// ---------------- DTW DP over anti-diagonals: one wave per batch --------------
// lane l owns rows i in [16l, 16l+16). At diagonal d, slot i computes cell
// (i, d-i):  cur[i] = c[i] + min(prev[i], prev[i-1], prev2[i-1]).
// 8-row fp32 ring (proven) + 16-ahead touch-prefetch. Each step issues
// 4 ring loads (row i+8) + 1 touch (row i+16): steady state 41 outstanding
// (<= 63 vmcnt cap); loads issued after ring_i = touch_{i+8} + 7 steps x 5
// = 36 -> vmcnt(36) exactly guarantees ring_i landed. Compute-before-wait:
// the min3 chain depends only on A/B and runs before the vmcnt.
__global__ __launch_bounds__(64)
__attribute__((amdgpu_waves_per_eu(1, 1)))
void dtw_diag_kernel(const float* __restrict__ cost, float* __restrict__ out) {
    const int b    = blockIdx.x;
    const int lane = threadIdx.x;
    const float* cbD = cost + (size_t)b * NN * MM;    // uniform across wave
    const unsigned voff = (unsigned)lane * 64u;       // 16 floats/lane

    RowBuf R0, R1, R2, R3, R4, R5, R6, R7;
    float dummy = 0.0f;
    // prologue groups k=0..7: [ring_k x4, touch_{k+8}] (matches steady state)
    issue_row(R0, cbD + 0 * (size_t)MM, voff);  touch_row(dummy, cbD +  8 * (size_t)MM, voff);
    issue_row(R1, cbD + 1 * (size_t)MM, voff);  touch_row(dummy, cbD +  9 * (size_t)MM, voff);
    issue_row(R2, cbD + 2 * (size_t)MM, voff);  touch_row(dummy, cbD + 10 * (size_t)MM, voff);
    issue_row(R3, cbD + 3 * (size_t)MM, voff);  touch_row(dummy, cbD + 11 * (size_t)MM, voff);
    issue_row(R4, cbD + 4 * (size_t)MM, voff);  touch_row(dummy, cbD + 12 * (size_t)MM, voff);
    issue_row(R5, cbD + 5 * (size_t)MM, voff);  touch_row(dummy, cbD + 13 * (size_t)MM, voff);
    issue_row(R6, cbD + 6 * (size_t)MM, voff);  touch_row(dummy, cbD + 14 * (size_t)MM, voff);
    issue_row(R7, cbD + 7 * (size_t)MM, voff);  touch_row(dummy, cbD + 15 * (size_t)MM, voff);

    float A[16], B[16];
    #pragma unroll
    for (int j = 0; j < 16; ++j) { A[j] = INF_; B[j] = INF_; }
    float bnd = 0.0f;    // diag-neighbor injected at (0,0) only; INF_ afterwards

    // one diagonal: min3 chain first (A/B only), THEN wait oldest ring row,
    // add, reissue ring (row NR) + touch (row NT). NR/NT always valid rows.
    #define DIAG_STEP(Rk, PV, P2, NR, NT)                                      \
    {                                                                          \
        float pvm1 = dpp_wave_shr1(PV[15], INF_);                              \
        float p2m1 = dpp_wave_shr1(P2[15], bnd);                               \
        float t[16];                                                           \
        _Pragma("unroll")                                                      \
        for (int r = 0; r < 16; ++r) {                                         \
            float pv_r = PV[r], p2_r = P2[r];                                  \
            t[r] = fminf(fminf(pv_r, pvm1), p2m1);                             \
            pvm1 = pv_r; p2m1 = p2_r;                                          \
        }                                                                      \
        asm volatile("s_waitcnt vmcnt(36)" ::: "memory");                      \
        __builtin_amdgcn_sched_barrier(0);                                     \
        float cc[16] = {Rk.q0[0], Rk.q0[1], Rk.q0[2], Rk.q0[3],                \
                        Rk.q1[0], Rk.q1[1], Rk.q1[2], Rk.q1[3],                \
                        Rk.q2[0], Rk.q2[1], Rk.q2[2], Rk.q2[3],                \
                        Rk.q3[0], Rk.q3[1], Rk.q3[2], Rk.q3[3]};               \
        _Pragma("unroll")                                                      \
        for (int r = 0; r < 16; ++r) P2[r] = cc[r] + t[r];                     \
        __builtin_amdgcn_sched_barrier(0);                                     \
        issue_row(Rk, cbD + (size_t)(NR) * MM, voff);                          \
        touch_row(dummy, cbD + (size_t)(NT) * MM, voff);                       \
    }

    // peel first 8 diagonals (d = 0..7); bnd -> INF_ after d = 0
    DIAG_STEP(R0, A, B, 8,  16)   bnd = INF_;
    DIAG_STEP(R1, B, A, 9,  17)
    DIAG_STEP(R2, A, B, 10, 18)
    DIAG_STEP(R3, B, A, 11, 19)
    DIAG_STEP(R4, A, B, 12, 20)
    DIAG_STEP(R5, B, A, 13, 21)
    DIAG_STEP(R6, A, B, 14, 22)
    DIAG_STEP(R7, B, A, 15, 23)

    for (int d0 = 8; d0 < 2040; d0 += 8) {
        DIAG_STEP(R0, A, B, ((d0 +  8) & 1023), ((d0 + 16) & 1023))
        DIAG_STEP(R1, B, A, ((d0 +  9) & 1023), ((d0 + 17) & 1023))
        DIAG_STEP(R2, A, B, ((d0 + 10) & 1023), ((d0 + 18) & 1023))
        DIAG_STEP(R3, B, A, ((d0 + 11) & 1023), ((d0 + 19) & 1023))
        DIAG_STEP(R4, A, B, ((d0 + 12) & 1023), ((d0 + 20) & 1023))
        DIAG_STEP(R5, B, A, ((d0 + 13) & 1023), ((d0 + 21) & 1023))
        DIAG_STEP(R6, A, B, ((d0 + 14) & 1023), ((d0 + 22) & 1023))
        DIAG_STEP(R7, B, A, ((d0 + 15) & 1023), ((d0 + 23) & 1023))
    }

    // tail: d = 2040..2046 (reissues are dummies, keep vmcnt invariant)
    DIAG_STEP(R0, A, B, 0, 16)
    DIAG_STEP(R1, B, A, 1, 17)
    DIAG_STEP(R2, A, B, 2, 18)
    DIAG_STEP(R3, B, A, 3, 19)
    DIAG_STEP(R4, A, B, 4, 20)
    DIAG_STEP(R5, B, A, 5, 21)
    DIAG_STEP(R6, A, B, 6, 22)      // d = 2046 writes B; D(1023,1023) = B[15]@lane63
    #undef DIAG_STEP

    asm volatile("" :: "v"(dummy));   // terminal use: keep touch reg reserved

    if (lane == 63) out[b] = B[15];
}

// ---------------- fused fallback (no workspace): cost on the fly --------------
__global__ __launch_bounds__(1024) void dtw_fused_kernel(const float* __restrict__ x,
                                                         const float* __restrict__ y,
                                                         float* __restrict__ out) {
    const int b    = blockIdx.x;
    const int tid  = threadIdx.x;
    const int lane = tid & 63;
    const int wid  = tid >> 6;
    __shared__ float P[MM];
    __shared__ float xrow[FF];
    __shared__ float part_sum[16];
    __shared__ float part_min[16];

    float yr[FF];
    const float* yrow = y + ((size_t)b * MM + tid) * FF;
    #pragma unroll
    for (int q = 0; q < FF / 4; ++q) {
        float4 v = ((const float4*)yrow)[q];
        yr[q*4+0] = v.x; yr[q*4+1] = v.y; yr[q*4+2] = v.z; yr[q*4+3] = v.w;
    }

    P[tid] = INF_;
    __syncthreads();

    const float* xb = x + (size_t)b * NN * FF;
    float result = 0.0f;

    for (int i = 0; i < NN; ++i) {
        if (tid < FF) xrow[tid] = xb[(size_t)i * FF + tid];
        float up   = P[tid];
        float diag = (tid == 0) ? (i == 0 ? 0.0f : INF_) : P[tid - 1];
        float m    = fminf(up, diag);
        __syncthreads();

        float ss = 0.0f;
        #pragma unroll 16
        for (int k = 0; k < FF; ++k) {
            float d = xrow[k] - yr[k];
            ss += d * d;
        }
        float c = sqrtf(ss);

        float s = c;
        #pragma unroll
        for (int d = 1; d < 64; d <<= 1) {
            float t = __shfl_up(s, d, 64);
            if (lane >= d) s += t;
        }
        if (lane == 63) part_sum[wid] = s;
        __syncthreads();
        if (tid < 16) {
            float p = part_sum[tid];
            #pragma unroll
            for (int d = 1; d < 16; d <<= 1) {
                float t = __shfl_up(p, d, 64);
                if (tid >= d) p += t;
            }
            part_sum[tid] = p;
        }
        __syncthreads();
        float C = s + (wid > 0 ? part_sum[wid - 1] : 0.0f);

        float z = c + m - C;
        float w = z;
        #pragma unroll
        for (int d = 1; d < 64; d <<= 1) {
            float t = __shfl_up(w, d, 64);
            if (lane >= d) w = fminf(w, t);
        }
        if (lane == 63) part_min[wid] = w;
        __syncthreads();
        if (tid < 16) {
            float p = part_min[tid];
            #pragma unroll
            for (int d = 1; d < 16; d <<= 1) {
                float t = __shfl_up(p, d, 64);
                if (tid >= d) p = fminf(p, t);
            }
            part_min[tid] = p;
        }
        __syncthreads();
        float wm  = (wid > 0) ? fminf(w, part_min[wid - 1]) : w;
        float cur = C + wm;

        P[tid] = cur;
        __syncthreads();
        if (i == NN - 1 && tid == MM - 1) result = cur;
    }
    if (tid == MM - 1) out[b] = result;
}

extern "C" void kernel_launch(void* const* d_in, const int* in_sizes, int n_in,
                              void* d_out, int out_size, void* d_ws, size_t ws_size,
                              hipStream_t stream) {
    const float* x = (const float*)d_in[0];
    const float* y = (const float*)d_in[1];
    float* out = (float*)d_out;

    size_t need = (size_t)BB * NN * MM * sizeof(float);

    if (ws_size >= need) {
        float* cost = (float*)d_ws;
        hipLaunchKernelGGL(cost_kernel, dim3(MM / 64, NN / 64, BB), dim3(256), 0, stream,
                           x, y, cost);
        hipLaunchKernelGGL(dtw_diag_kernel, dim3(BB), dim3(64), 0, stream, cost, out);
    } else {
        hipLaunchKernelGGL(dtw_fused_kernel, dim3(BB), dim3(1024), 0, stream, x, y, out);
    }
}